// Round 15
// baseline (184.594 us; speedup 1.0000x reference)
//
#include <hip/hip_runtime.h>
#include <math.h>

#define Bn 16
#define Cn 64
#define Hn 192
#define Wn 192
#define TH 16
#define TW 16
#define NPIX (Bn * Cn * Hn * Wn)       // 37748736
#define NBLKS 256
#define TPB 9                          // 3x3 tile patch per persistent block
#define XW_BYTES (18 * 18 * 128)       // 41472

typedef short bf16x8 __attribute__((ext_vector_type(8)));
typedef float f32x4 __attribute__((ext_vector_type(4)));
typedef __attribute__((address_space(1))) const unsigned int as1_u32;
typedef __attribute__((address_space(3))) unsigned int as3_u32;

// g_Ms[9 slices][64 rows][64 c] bf16; within a row, c-octet g stored at slot (g ^ (row&7)).
__device__ __align__(16) unsigned short g_Ms[9 * 64 * 64];
__device__ __align__(16) float g_b2[64];

static __device__ __forceinline__ unsigned short f2bf(float f) {
    union { float f; unsigned u; } x; x.f = f;
    unsigned r = x.u + 0x7fffu + ((x.u >> 16) & 1u);   // RNE
    return (unsigned short)(r >> 16);
}

__global__ void acdc_precompute(const float* __restrict__ cw, const float* __restrict__ A,
                                const float* __restrict__ D, const float* __restrict__ bias,
                                const int* __restrict__ perm) {
    __shared__ float mre[64];
    int p = blockIdx.x;
    int t = threadIdx.x;
    if (t < 64) {
        float re = 0.f;
        for (int k = 0; k < 64; ++k) {
            int a = (k * t) & 63;
            re += D[k] * cosf((float)a * 0.0981747704246810387f);  // pi/32
        }
        mre[t] = re;
    }
    __syncthreads();
    int pp = perm[p];
    for (int k0 = t; k0 < 576; k0 += 256) {
        int sp = k0 >> 6, c = k0 & 63;
        int g = c >> 3, cil = c & 7;
        float val = 0.f;
        for (int o = 0; o < 8; ++o) {
            int oc = g * 8 + o;
            float gco = mre[(pp - oc + 64) & 63] * A[oc] * (0.125f / 64.0f);
            val += gco * cw[(oc * 8 + cil) * 9 + sp];
        }
        g_Ms[((sp * 64 + p) << 6) + (((g ^ (p & 7)) << 3) | cil)] = f2bf(val);
    }
    if (p == 0 && t < 64)
        g_b2[t] = bias[perm[t]] * 0.125f;
}

// Persistent block: 1024 threads, 1 block/CU. M in LDS once (72 KB).
// xsb DOUBLE-buffered (2x41.5 KB; total 156.7 KB <= 160 KiB): xwrite(t+1) overlaps
// compute(t); ONE barrier per tile. Wave tiling 2m x 8px: 4 reads per 4 MFMAs.
__global__ __launch_bounds__(1024)
void acdc_main(const float* __restrict__ x, float* __restrict__ out) {
    __shared__ __align__(16) unsigned short Mlds[9 * 64 * 64];   // 73728 B
    __shared__ __align__(16) unsigned char xsb[2][XW_BYTES];     // 82944 B

    int tid = threadIdx.x;
    int lane = tid & 63, wv = tid >> 6;
    // bijective XCD swizzle: XCD x gets logical blocks [x*32, x*32+32) = 2 whole batches
    int Lb = (blockIdx.x & 7) * (NBLKS / 8) + (blockIdx.x >> 3);
    int pid = Lb & 15, batch = Lb >> 4;
    int pr = pid >> 2, pc = pid & 3;     // patch coords in 4x4 grid

    // ---- stage M once: 72 x 1KB chunks via global_load_lds ----
    #pragma unroll
    for (int k = 0; k < 5; ++k) {
        int chunk = wv + k * 16;
        if (chunk < 72) {
            const unsigned char* src = (const unsigned char*)g_Ms + chunk * 1024 + lane * 16;
            __builtin_amdgcn_global_load_lds((as1_u32*)(const void*)src,
                (as3_u32*)(void*)((unsigned char*)Mlds + chunk * 1024), 16, 0, 0);
        }
    }

    int pxw = lane & 15, q = lane >> 4, rlane = lane & 15;
    int pg = wv & 7, mg = wv >> 3;       // wave = (m-group, px-group)
    int prow = pg * 2;                   // this wave's 2 pixel rows

    int bb = batch, h0 = 0, w0 = 0; bool edge = false;
    auto decode = [&](int t) {
        int bh = pr * 3 + t / 3, bw = pc * 3 + t % 3;
        h0 = bh * TH; w0 = bw * TW;
        edge = (bh == 0) | (bh == 11) | (bw == 0) | (bw == 11);
    };

    // ---- x stage: load phase (to regs) and write phase (cvt + ds_write) ----
    float4 va[4], vb[4];
    auto xload = [&](int t) {
        decode(t);
        const float* xb = x + (size_t)bb * Cn * Hn * Wn;
        #pragma unroll
        for (int k = 0; k < 4; ++k) {
            int idx = tid + (k << 10);
            if (idx >= 3456) break;
            int f = idx % 6;
            int rr = (idx / 6) % 18;
            int cp = idx / 108;
            int gh = h0 + rr - 1;
            int gwf = w0 + f * 4 - 4;
            const float* row0 = xb + ((size_t)(cp * 2) * Hn + gh) * Wn;
            const float* row1 = row0 + (size_t)(Hn * Wn);
            if (!edge) {
                va[k] = *(const float4*)(row0 + gwf);
                vb[k] = *(const float4*)(row1 + gwf);
            } else {
                bool ghok = (unsigned)gh < (unsigned)Hn;
                if (ghok && gwf >= 0 && gwf <= Wn - 4) {
                    va[k] = *(const float4*)(row0 + gwf);
                    vb[k] = *(const float4*)(row1 + gwf);
                } else {
                    float t0[4], t1[4];
                    #pragma unroll
                    for (int j = 0; j < 4; ++j) {
                        int gw = gwf + j;
                        bool ok = ghok && (unsigned)gw < (unsigned)Wn;
                        t0[j] = ok ? row0[gw] : 0.f;
                        t1[j] = ok ? row1[gw] : 0.f;
                    }
                    va[k] = (float4){t0[0], t0[1], t0[2], t0[3]};
                    vb[k] = (float4){t1[0], t1[1], t1[2], t1[3]};
                }
            }
        }
    };
    auto xwrite = [&](unsigned char* dst) {
        #pragma unroll
        for (int k = 0; k < 4; ++k) {
            int idx = tid + (k << 10);
            if (idx >= 3456) break;
            int f = idx % 6;
            int rr = (idx / 6) % 18;
            int cp = idx / 108;
            int chunk = cp >> 2;
            int sub = (cp & 3) * 4;
            float v0[4] = {va[k].x, va[k].y, va[k].z, va[k].w};
            float v1[4] = {vb[k].x, vb[k].y, vb[k].z, vb[k].w};
            #pragma unroll
            for (int j = 0; j < 4; ++j) {
                int col = f * 4 + j - 3;
                if ((unsigned)col >= 18u) continue;
                unsigned u;
                asm("v_cvt_pk_bf16_f32 %0, %1, %2" : "=v"(u) : "v"(v0[j]), "v"(v1[j]));
                int byte = (rr * 18 + col) * 128 + ((chunk ^ ((col + 3 * rr) & 7)) * 16) + sub;
                *(unsigned*)(dst + byte) = u;
            }
        }
    };

    xload(0);
    xwrite(xsb[0]);
    __syncthreads();   // publishes M + x(0)

    for (int t = 0; t < TPB; ++t) {
        decode(t);
        int ch0 = h0, cw0 = w0;
        const unsigned char* cur = xsb[t & 1];
        unsigned char* nxt = xsb[(t + 1) & 1];
        if (t + 1 < TPB) xload(t + 1);   // issue next tile's global loads

        f32x4 acc[2][2];
        #pragma unroll
        for (int mi = 0; mi < 2; ++mi)
            #pragma unroll
            for (int ni = 0; ni < 2; ++ni)
                acc[mi][ni] = (f32x4){0.f, 0.f, 0.f, 0.f};

        // ---- compute: 2 A-reads + 2 B-reads per 4 MFMAs, barrier-free ----
        auto phases = [&](int spLo, int spHi) {
            #pragma unroll
            for (int sp = 0; sp < 9; ++sp) {
                if (sp < spLo || sp >= spHi) continue;
                const int dy = sp / 3, dx = sp % 3;
                int col = pxw + dx;
                #pragma unroll
                for (int kh = 0; kh < 2; ++kh) {
                    int ksl = kh * 4 + q;
                    bf16x8 bfr[2];
                    #pragma unroll
                    for (int ni = 0; ni < 2; ++ni) {
                        int row = prow + ni + dy;
                        bfr[ni] = *(const bf16x8*)(cur + (row * 18 + col) * 128 +
                                    ((ksl ^ ((col + 3 * row) & 7)) << 4));
                    }
                    const unsigned char* mbase = (const unsigned char*)Mlds + sp * 8192 +
                                                 rlane * 128 + ((ksl ^ (rlane & 7)) << 4);
                    __builtin_amdgcn_s_setprio(1);
                    #pragma unroll
                    for (int mi = 0; mi < 2; ++mi) {
                        bf16x8 am = *(const bf16x8*)(mbase + (mg * 2 + mi) * 2048);
                        #pragma unroll
                        for (int ni = 0; ni < 2; ++ni)
                            acc[mi][ni] = __builtin_amdgcn_mfma_f32_16x16x32_bf16(
                                am, bfr[ni], acc[mi][ni], 0, 0, 0);
                    }
                    __builtin_amdgcn_s_setprio(0);
                }
            }
        };

        phases(0, 4);
        if (t + 1 < TPB) xwrite(nxt);    // overlaps with remaining compute (other buffer)
        phases(4, 9);

        // ---- epilogue: +bias, real-only coalesced stores ----
        #pragma unroll
        for (int mi = 0; mi < 2; ++mi) {
            int rbase = (mg * 2 + mi) * 16 + q * 4;
            float4 bq = *(const float4*)(g_b2 + rbase);
            #pragma unroll
            for (int ni = 0; ni < 2; ++ni) {
                float* orow = out + (((size_t)(bb * Cn + rbase)) * Hn + (ch0 + prow + ni)) * Wn
                              + cw0 + pxw;
                orow[0]                   = acc[mi][ni][0] + bq.x;
                orow[(size_t)Hn * Wn]     = acc[mi][ni][1] + bq.y;
                orow[(size_t)2 * Hn * Wn] = acc[mi][ni][2] + bq.z;
                orow[(size_t)3 * Hn * Wn] = acc[mi][ni][3] + bq.w;
            }
        }

        __syncthreads();   // publishes x(t+1) writes; protects buffer reuse
    }
}

extern "C" void kernel_launch(void* const* d_in, const int* in_sizes, int n_in,
                              void* d_out, int out_size, void* d_ws, size_t ws_size,
                              hipStream_t stream) {
    const float* x    = (const float*)d_in[0];
    const float* cw   = (const float*)d_in[1];
    const float* A    = (const float*)d_in[2];
    const float* D    = (const float*)d_in[3];
    const float* bias = (const float*)d_in[4];
    const int*   perm = (const int*)d_in[5];

    acdc_precompute<<<dim3(64), dim3(256), 0, stream>>>(cw, A, D, bias, perm);
    acdc_main<<<dim3(NBLKS), dim3(1024), 0, stream>>>(x, (float*)d_out);
}

// Round 16
// 168.204 us; speedup vs baseline: 1.0974x; 1.0974x over previous
//
#include <hip/hip_runtime.h>
#include <math.h>

#define Bn 16
#define Cn 64
#define Hn 192
#define Wn 192
#define TH 16
#define TW 16
#define NPIX (Bn * Cn * Hn * Wn)       // 37748736
#define NBLKS 256
#define TPB 9                          // 3x3 tile patch per persistent block
#define XW_BYTES (18 * 18 * 128)       // 41472

typedef short bf16x8 __attribute__((ext_vector_type(8)));
typedef float f32x4 __attribute__((ext_vector_type(4)));
typedef __attribute__((address_space(1))) const unsigned int as1_u32;
typedef __attribute__((address_space(3))) unsigned int as3_u32;

// g_Ms[9 slices][64 rows][64 c] bf16; within a row, c-octet g stored at slot (g ^ (row&7)).
__device__ __align__(16) unsigned short g_Ms[9 * 64 * 64];
__device__ __align__(16) float g_b2[64];

static __device__ __forceinline__ unsigned short f2bf(float f) {
    union { float f; unsigned u; } x; x.f = f;
    unsigned r = x.u + 0x7fffu + ((x.u >> 16) & 1u);   // RNE
    return (unsigned short)(r >> 16);
}

__global__ void acdc_precompute(const float* __restrict__ cw, const float* __restrict__ A,
                                const float* __restrict__ D, const float* __restrict__ bias,
                                const int* __restrict__ perm) {
    __shared__ float mre[64];
    int p = blockIdx.x;
    int t = threadIdx.x;
    if (t < 64) {
        float re = 0.f;
        for (int k = 0; k < 64; ++k) {
            int a = (k * t) & 63;
            re += D[k] * cosf((float)a * 0.0981747704246810387f);  // pi/32
        }
        mre[t] = re;
    }
    __syncthreads();
    int pp = perm[p];
    for (int k0 = t; k0 < 576; k0 += 256) {
        int sp = k0 >> 6, c = k0 & 63;
        int g = c >> 3, cil = c & 7;
        float val = 0.f;
        for (int o = 0; o < 8; ++o) {
            int oc = g * 8 + o;
            float gco = mre[(pp - oc + 64) & 63] * A[oc] * (0.125f / 64.0f);
            val += gco * cw[(oc * 8 + cil) * 9 + sp];
        }
        g_Ms[((sp * 64 + p) << 6) + (((g ^ (p & 7)) << 3) | cil)] = f2bf(val);
    }
    if (p == 0 && t < 64)
        g_b2[t] = bias[perm[t]] * 0.125f;
}

// Persistent block: 1024 threads, 1 block/CU (LDS 115 KB). M staged ONCE.
// R14 skeleton; ONE change: 2m x 2row wave tiling (32x32/wave) -> 4 LDS reads
// per 4 MFMAs (was 5/4). Compute inline, NO lambda (R15's acc-in-lambda spilled).
__global__ __launch_bounds__(1024)
void acdc_main(const float* __restrict__ x, float* __restrict__ out) {
    __shared__ __align__(16) unsigned short Mlds[9 * 64 * 64];   // 73728 B
    __shared__ __align__(16) unsigned char xsb[XW_BYTES];        // 41472 B

    int tid = threadIdx.x;
    int lane = tid & 63, wv = tid >> 6;
    // bijective XCD swizzle: XCD x gets logical blocks [x*32, x*32+32) = 2 whole batches
    int Lb = (blockIdx.x & 7) * (NBLKS / 8) + (blockIdx.x >> 3);
    int pid = Lb & 15, batch = Lb >> 4;
    int pr = pid >> 2, pc = pid & 3;     // patch coords in 4x4 grid

    // ---- stage M once: 72 x 1KB chunks via global_load_lds ----
    #pragma unroll
    for (int k = 0; k < 5; ++k) {
        int chunk = wv + k * 16;
        if (chunk < 72) {
            const unsigned char* src = (const unsigned char*)g_Ms + chunk * 1024 + lane * 16;
            __builtin_amdgcn_global_load_lds((as1_u32*)(const void*)src,
                (as3_u32*)(void*)((unsigned char*)Mlds + chunk * 1024), 16, 0, 0);
        }
    }

    int pxw = lane & 15, q = lane >> 4, rlane = lane & 15;
    int pg = wv & 7, mg = wv >> 3;       // wave = (px-row-group, m-group)
    int prow = pg * 2;                   // this wave's 2 pixel rows

    int bb = batch, h0 = 0, w0 = 0; bool edge = false;
    auto decode = [&](int t) {
        int bh = pr * 3 + t / 3, bw = pc * 3 + t % 3;
        h0 = bh * TH; w0 = bw * TW;
        edge = (bh == 0) | (bh == 11) | (bw == 0) | (bw == 11);
    };

    // ---- x stage: load phase (to regs) and write phase (cvt + ds_write) ----
    float4 va[4], vb[4];
    auto xload = [&](int t) {
        decode(t);
        const float* xb = x + (size_t)bb * Cn * Hn * Wn;
        #pragma unroll
        for (int k = 0; k < 4; ++k) {
            int idx = tid + (k << 10);
            if (idx >= 3456) break;
            int f = idx % 6;
            int rr = (idx / 6) % 18;
            int cp = idx / 108;
            int gh = h0 + rr - 1;
            int gwf = w0 + f * 4 - 4;
            const float* row0 = xb + ((size_t)(cp * 2) * Hn + gh) * Wn;
            const float* row1 = row0 + (size_t)(Hn * Wn);
            if (!edge) {
                va[k] = *(const float4*)(row0 + gwf);
                vb[k] = *(const float4*)(row1 + gwf);
            } else {
                bool ghok = (unsigned)gh < (unsigned)Hn;
                if (ghok && gwf >= 0 && gwf <= Wn - 4) {
                    va[k] = *(const float4*)(row0 + gwf);
                    vb[k] = *(const float4*)(row1 + gwf);
                } else {
                    float t0[4], t1[4];
                    #pragma unroll
                    for (int j = 0; j < 4; ++j) {
                        int gw = gwf + j;
                        bool ok = ghok && (unsigned)gw < (unsigned)Wn;
                        t0[j] = ok ? row0[gw] : 0.f;
                        t1[j] = ok ? row1[gw] : 0.f;
                    }
                    va[k] = (float4){t0[0], t0[1], t0[2], t0[3]};
                    vb[k] = (float4){t1[0], t1[1], t1[2], t1[3]};
                }
            }
        }
    };
    auto xwrite = [&]() {
        #pragma unroll
        for (int k = 0; k < 4; ++k) {
            int idx = tid + (k << 10);
            if (idx >= 3456) break;
            int f = idx % 6;
            int rr = (idx / 6) % 18;
            int cp = idx / 108;
            int chunk = cp >> 2;
            int sub = (cp & 3) * 4;
            float v0[4] = {va[k].x, va[k].y, va[k].z, va[k].w};
            float v1[4] = {vb[k].x, vb[k].y, vb[k].z, vb[k].w};
            #pragma unroll
            for (int j = 0; j < 4; ++j) {
                int col = f * 4 + j - 3;
                if ((unsigned)col >= 18u) continue;
                unsigned u;
                asm("v_cvt_pk_bf16_f32 %0, %1, %2" : "=v"(u) : "v"(v0[j]), "v"(v1[j]));
                int byte = (rr * 18 + col) * 128 + ((chunk ^ ((col + 3 * rr) & 7)) * 16) + sub;
                *(unsigned*)(xsb + byte) = u;
            }
        }
    };

    xload(0);
    xwrite();
    __syncthreads();   // publishes M + x(0)

    for (int t = 0; t < TPB; ++t) {
        decode(t);
        int ch0 = h0, cw0 = w0;
        if (t + 1 < TPB) xload(t + 1);   // issue next tile's loads; retire under compute

        // ---- compute tile t: inline, barrier-free, fully unrolled ----
        f32x4 acc[2][2];
        #pragma unroll
        for (int mi = 0; mi < 2; ++mi)
            #pragma unroll
            for (int ni = 0; ni < 2; ++ni)
                acc[mi][ni] = (f32x4){0.f, 0.f, 0.f, 0.f};

        #pragma unroll
        for (int sp = 0; sp < 9; ++sp) {
            const int dy = sp / 3, dx = sp % 3;
            int col = pxw + dx;
            #pragma unroll
            for (int kh = 0; kh < 2; ++kh) {
                int ksl = kh * 4 + q;
                bf16x8 bfr[2];
                #pragma unroll
                for (int ni = 0; ni < 2; ++ni) {
                    int row = prow + ni + dy;
                    bfr[ni] = *(const bf16x8*)(xsb + (row * 18 + col) * 128 +
                                ((ksl ^ ((col + 3 * row) & 7)) << 4));
                }
                const unsigned char* mbase = (const unsigned char*)Mlds + sp * 8192 +
                                             rlane * 128 + ((ksl ^ (rlane & 7)) << 4);
                __builtin_amdgcn_s_setprio(1);
                #pragma unroll
                for (int mi = 0; mi < 2; ++mi) {
                    bf16x8 am = *(const bf16x8*)(mbase + (mg * 2 + mi) * 2048);
                    #pragma unroll
                    for (int ni = 0; ni < 2; ++ni)
                        acc[mi][ni] = __builtin_amdgcn_mfma_f32_16x16x32_bf16(
                            am, bfr[ni], acc[mi][ni], 0, 0, 0);
                }
                __builtin_amdgcn_s_setprio(0);
            }
        }

        // ---- epilogue: +bias, real-only coalesced stores ----
        #pragma unroll
        for (int mi = 0; mi < 2; ++mi) {
            int rbase = (mg * 2 + mi) * 16 + q * 4;
            float4 bq = *(const float4*)(g_b2 + rbase);
            #pragma unroll
            for (int ni = 0; ni < 2; ++ni) {
                float* orow = out + (((size_t)(bb * Cn + rbase)) * Hn + (ch0 + prow + ni)) * Wn
                              + cw0 + pxw;
                orow[0]                   = acc[mi][ni][0] + bq.x;
                orow[(size_t)Hn * Wn]     = acc[mi][ni][1] + bq.y;
                orow[(size_t)2 * Hn * Wn] = acc[mi][ni][2] + bq.z;
                orow[(size_t)3 * Hn * Wn] = acc[mi][ni][3] + bq.w;
            }
        }

        __syncthreads();                 // all xsb reads for tile t done
        if (t + 1 < TPB) {
            xwrite();                    // cvt + ds_write next tile
        }
        __syncthreads();                 // publish x(t+1)
    }
}

extern "C" void kernel_launch(void* const* d_in, const int* in_sizes, int n_in,
                              void* d_out, int out_size, void* d_ws, size_t ws_size,
                              hipStream_t stream) {
    const float* x    = (const float*)d_in[0];
    const float* cw   = (const float*)d_in[1];
    const float* A    = (const float*)d_in[2];
    const float* D    = (const float*)d_in[3];
    const float* bias = (const float*)d_in[4];
    const int*   perm = (const int*)d_in[5];

    acdc_precompute<<<dim3(64), dim3(256), 0, stream>>>(cw, A, D, bias, perm);
    acdc_main<<<dim3(NBLKS), dim3(1024), 0, stream>>>(x, (float*)d_out);
}

// Round 17
// 166.003 us; speedup vs baseline: 1.1120x; 1.0133x over previous
//
#include <hip/hip_runtime.h>
#include <math.h>

#define Bn 16
#define Cn 64
#define Hn 192
#define Wn 192
#define TH 16
#define TW 16
#define NPIX (Bn * Cn * Hn * Wn)       // 37748736
#define NBLKS 256
#define TPB 9                          // 3x3 tile patch per persistent block
#define XW_BYTES (18 * 18 * 128)       // 41472

typedef short bf16x8 __attribute__((ext_vector_type(8)));
typedef float f32x4 __attribute__((ext_vector_type(4)));
typedef __attribute__((address_space(1))) const unsigned int as1_u32;
typedef __attribute__((address_space(3))) unsigned int as3_u32;

// g_Ms[9 slices][64 rows][64 c] bf16; within a row, c-octet g stored at slot (g ^ (row&7)).
__device__ __align__(16) unsigned short g_Ms[9 * 64 * 64];
__device__ __align__(16) float g_b2[64];

static __device__ __forceinline__ unsigned short f2bf(float f) {
    union { float f; unsigned u; } x; x.f = f;
    unsigned r = x.u + 0x7fffu + ((x.u >> 16) & 1u);   // RNE
    return (unsigned short)(r >> 16);
}

__global__ void acdc_precompute(const float* __restrict__ cw, const float* __restrict__ A,
                                const float* __restrict__ D, const float* __restrict__ bias,
                                const int* __restrict__ perm) {
    __shared__ float mre[64];
    int p = blockIdx.x;
    int t = threadIdx.x;
    if (t < 64) {
        float re = 0.f;
        for (int k = 0; k < 64; ++k) {
            int a = (k * t) & 63;
            re += D[k] * cosf((float)a * 0.0981747704246810387f);  // pi/32
        }
        mre[t] = re;
    }
    __syncthreads();
    int pp = perm[p];
    for (int k0 = t; k0 < 576; k0 += 256) {
        int sp = k0 >> 6, c = k0 & 63;
        int g = c >> 3, cil = c & 7;
        float val = 0.f;
        for (int o = 0; o < 8; ++o) {
            int oc = g * 8 + o;
            float gco = mre[(pp - oc + 64) & 63] * A[oc] * (0.125f / 64.0f);
            val += gco * cw[(oc * 8 + cil) * 9 + sp];
        }
        g_Ms[((sp * 64 + p) << 6) + (((g ^ (p & 7)) << 3) | cil)] = f2bf(val);
    }
    if (p == 0 && t < 64)
        g_b2[t] = bias[perm[t]] * 0.125f;
}

// Persistent block: 1024 threads, 1 block/CU. M staged ONCE (72 KB).
// R14 EXACT wave decomposition (wave=row, acc[4], am[4]) — mg/pg variants (R15/R16)
// both triggered a +119MB FETCH codegen anomaly. One change vs R14: xsb double-buffered
// (LDS 156.7 KB), xwrite(t+1) inside tile body, ONE barrier per tile (was 2).
__global__ __launch_bounds__(1024)
void acdc_main(const float* __restrict__ x, float* __restrict__ out) {
    __shared__ __align__(16) unsigned short Mlds[9 * 64 * 64];   // 73728 B
    __shared__ __align__(16) unsigned char xsb[2][XW_BYTES];     // 82944 B

    int tid = threadIdx.x;
    int lane = tid & 63, wv = tid >> 6;
    // bijective XCD swizzle: XCD x gets logical blocks [x*32, x*32+32) = 2 whole batches
    int Lb = (blockIdx.x & 7) * (NBLKS / 8) + (blockIdx.x >> 3);
    int pid = Lb & 15, batch = Lb >> 4;
    int pr = pid >> 2, pc = pid & 3;     // patch coords in 4x4 grid

    // ---- stage M once: 72 x 1KB chunks via global_load_lds ----
    #pragma unroll
    for (int k = 0; k < 5; ++k) {
        int chunk = wv + k * 16;
        if (chunk < 72) {
            const unsigned char* src = (const unsigned char*)g_Ms + chunk * 1024 + lane * 16;
            __builtin_amdgcn_global_load_lds((as1_u32*)(const void*)src,
                (as3_u32*)(void*)((unsigned char*)Mlds + chunk * 1024), 16, 0, 0);
        }
    }

    int pxw = lane & 15, q = lane >> 4, rlane = lane & 15;

    int bb = batch, h0 = 0, w0 = 0; bool edge = false;
    auto decode = [&](int t) {
        int bh = pr * 3 + t / 3, bw = pc * 3 + t % 3;
        h0 = bh * TH; w0 = bw * TW;
        edge = (bh == 0) | (bh == 11) | (bw == 0) | (bw == 11);
    };

    // ---- x stage: load phase (to regs) and write phase (cvt + ds_write) ----
    float4 va[4], vb[4];
    auto xload = [&](int t) {
        decode(t);
        const float* xb = x + (size_t)bb * Cn * Hn * Wn;
        #pragma unroll
        for (int k = 0; k < 4; ++k) {
            int idx = tid + (k << 10);
            if (idx >= 3456) break;
            int f = idx % 6;
            int rr = (idx / 6) % 18;
            int cp = idx / 108;
            int gh = h0 + rr - 1;
            int gwf = w0 + f * 4 - 4;
            const float* row0 = xb + ((size_t)(cp * 2) * Hn + gh) * Wn;
            const float* row1 = row0 + (size_t)(Hn * Wn);
            if (!edge) {
                va[k] = *(const float4*)(row0 + gwf);
                vb[k] = *(const float4*)(row1 + gwf);
            } else {
                bool ghok = (unsigned)gh < (unsigned)Hn;
                if (ghok && gwf >= 0 && gwf <= Wn - 4) {
                    va[k] = *(const float4*)(row0 + gwf);
                    vb[k] = *(const float4*)(row1 + gwf);
                } else {
                    float t0[4], t1[4];
                    #pragma unroll
                    for (int j = 0; j < 4; ++j) {
                        int gw = gwf + j;
                        bool ok = ghok && (unsigned)gw < (unsigned)Wn;
                        t0[j] = ok ? row0[gw] : 0.f;
                        t1[j] = ok ? row1[gw] : 0.f;
                    }
                    va[k] = (float4){t0[0], t0[1], t0[2], t0[3]};
                    vb[k] = (float4){t1[0], t1[1], t1[2], t1[3]};
                }
            }
        }
    };
    auto xwrite = [&](unsigned char* dst) {
        #pragma unroll
        for (int k = 0; k < 4; ++k) {
            int idx = tid + (k << 10);
            if (idx >= 3456) break;
            int f = idx % 6;
            int rr = (idx / 6) % 18;
            int cp = idx / 108;
            int chunk = cp >> 2;
            int sub = (cp & 3) * 4;
            float v0[4] = {va[k].x, va[k].y, va[k].z, va[k].w};
            float v1[4] = {vb[k].x, vb[k].y, vb[k].z, vb[k].w};
            #pragma unroll
            for (int j = 0; j < 4; ++j) {
                int col = f * 4 + j - 3;
                if ((unsigned)col >= 18u) continue;
                unsigned u;
                asm("v_cvt_pk_bf16_f32 %0, %1, %2" : "=v"(u) : "v"(v0[j]), "v"(v1[j]));
                int byte = (rr * 18 + col) * 128 + ((chunk ^ ((col + 3 * rr) & 7)) * 16) + sub;
                *(unsigned*)(dst + byte) = u;
            }
        }
    };

    xload(0);
    xwrite(xsb[0]);
    __syncthreads();   // publishes M + x(0)

    for (int t = 0; t < TPB; ++t) {
        decode(t);
        int ch0 = h0, cw0 = w0;
        const unsigned char* cur = xsb[t & 1];
        unsigned char* nxt = xsb[(t + 1) & 1];
        if (t + 1 < TPB) xload(t + 1);   // issue next tile's loads; retire under compute

        // ---- compute tile t: R14-exact inline, barrier-free, fully unrolled ----
        f32x4 acc[4];
        #pragma unroll
        for (int m = 0; m < 4; ++m) acc[m] = (f32x4){0.f, 0.f, 0.f, 0.f};

        #pragma unroll
        for (int sp = 0; sp < 9; ++sp) {
            const int dy = sp / 3, dx = sp % 3;
            int col = pxw + dx;
            int row = wv + dy;
            int bbase = (row * 18 + col) * 128;
            int bswz = (col + 3 * row) & 7;
            #pragma unroll
            for (int kh = 0; kh < 2; ++kh) {
                int ksl = kh * 4 + q;
                bf16x8 bfr = *(const bf16x8*)(cur + bbase + ((ksl ^ bswz) << 4));
                const unsigned char* mrow = (const unsigned char*)Mlds + sp * 8192 +
                                            rlane * 128 + ((ksl ^ (rlane & 7)) << 4);
                __builtin_amdgcn_s_setprio(1);
                #pragma unroll
                for (int m = 0; m < 4; ++m) {
                    bf16x8 am = *(const bf16x8*)(mrow + m * 2048);
                    acc[m] = __builtin_amdgcn_mfma_f32_16x16x32_bf16(am, bfr, acc[m], 0, 0, 0);
                }
                __builtin_amdgcn_s_setprio(0);
            }
        }

        if (t + 1 < TPB) xwrite(nxt);    // other buffer: overlaps late waves' compute

        // ---- epilogue: +bias, real-only stores (wave wv owns output row ch0+wv) ----
        #pragma unroll
        for (int m = 0; m < 4; ++m) {
            int rbase = m * 16 + q * 4;
            float4 bq = *(const float4*)(g_b2 + rbase);
            float* orow = out + (((size_t)(bb * Cn + rbase)) * Hn + (ch0 + wv)) * Wn + cw0 + pxw;
            orow[0]                      = acc[m][0] + bq.x;
            orow[(size_t)Hn * Wn]        = acc[m][1] + bq.y;
            orow[(size_t)2 * Hn * Wn]    = acc[m][2] + bq.z;
            orow[(size_t)3 * Hn * Wn]    = acc[m][3] + bq.w;
        }

        __syncthreads();   // single barrier: publishes x(t+1), fences buffer reuse
    }
}

extern "C" void kernel_launch(void* const* d_in, const int* in_sizes, int n_in,
                              void* d_out, int out_size, void* d_ws, size_t ws_size,
                              hipStream_t stream) {
    const float* x    = (const float*)d_in[0];
    const float* cw   = (const float*)d_in[1];
    const float* A    = (const float*)d_in[2];
    const float* D    = (const float*)d_in[3];
    const float* bias = (const float*)d_in[4];
    const int*   perm = (const int*)d_in[5];

    acdc_precompute<<<dim3(64), dim3(256), 0, stream>>>(cw, A, D, bias, perm);
    acdc_main<<<dim3(NBLKS), dim3(1024), 0, stream>>>(x, (float*)d_out);
}

// Round 18
// 116.818 us; speedup vs baseline: 1.5802x; 1.4210x over previous
//
#include <hip/hip_runtime.h>
#include <math.h>

#define Bn 16
#define Cn 64
#define Hn 192
#define Wn 192
#define TH 16
#define TW 16
#define NPIX (Bn * Cn * Hn * Wn)       // 37748736
#define NBLKS 256
#define TPB 9                          // 9 vertically-consecutive tiles (column-major strip)
#define XW_BYTES (18 * 18 * 128)       // 41472

typedef short bf16x8 __attribute__((ext_vector_type(8)));
typedef float f32x4 __attribute__((ext_vector_type(4)));
typedef __attribute__((address_space(1))) const unsigned int as1_u32;
typedef __attribute__((address_space(3))) unsigned int as3_u32;

// g_Ms[9 slices][64 rows][64 c] bf16; within a row, c-octet g stored at slot (g ^ (row&7)).
__device__ __align__(16) unsigned short g_Ms[9 * 64 * 64];
__device__ __align__(16) float g_b2[64];

static __device__ __forceinline__ unsigned short f2bf(float f) {
    union { float f; unsigned u; } x; x.f = f;
    unsigned r = x.u + 0x7fffu + ((x.u >> 16) & 1u);   // RNE
    return (unsigned short)(r >> 16);
}

__global__ void acdc_precompute(const float* __restrict__ cw, const float* __restrict__ A,
                                const float* __restrict__ D, const float* __restrict__ bias,
                                const int* __restrict__ perm) {
    __shared__ float mre[64];
    int p = blockIdx.x;
    int t = threadIdx.x;
    if (t < 64) {
        float re = 0.f;
        for (int k = 0; k < 64; ++k) {
            int a = (k * t) & 63;
            re += D[k] * cosf((float)a * 0.0981747704246810387f);  // pi/32
        }
        mre[t] = re;
    }
    __syncthreads();
    int pp = perm[p];
    for (int k0 = t; k0 < 576; k0 += 256) {
        int sp = k0 >> 6, c = k0 & 63;
        int g = c >> 3, cil = c & 7;
        float val = 0.f;
        for (int o = 0; o < 8; ++o) {
            int oc = g * 8 + o;
            float gco = mre[(pp - oc + 64) & 63] * A[oc] * (0.125f / 64.0f);
            val += gco * cw[(oc * 8 + cil) * 9 + sp];
        }
        g_Ms[((sp * 64 + p) << 6) + (((g ^ (p & 7)) << 3) | cil)] = f2bf(val);
    }
    if (p == 0 && t < 64)
        g_b2[t] = bias[perm[t]] * 0.125f;
}

// Persistent block: 1024 threads, 1 block/CU. M staged ONCE (72 KB). R14 skeleton
// (single xsb, 2 barriers/tile, wave=row decomp). ONE change: column-major strip
// traversal + circular-row sliding window — tiles after the first load only 16 NEW
// rows (slot = (gh+1) % 18) instead of all 18 -> x HBM fetch ~= unique bytes.
__global__ __launch_bounds__(1024)
void acdc_main(const float* __restrict__ x, float* __restrict__ out) {
    __shared__ __align__(16) unsigned short Mlds[9 * 64 * 64];   // 73728 B
    __shared__ __align__(16) unsigned char xsb[XW_BYTES];        // 41472 B

    int tid = threadIdx.x;
    int lane = tid & 63, wv = tid >> 6;
    // bijective XCD swizzle: XCD x gets logical strips [x*32, x*32+32) = 2 whole batches
    int Lb = (blockIdx.x & 7) * (NBLKS / 8) + (blockIdx.x >> 3);

    // ---- stage M once: 72 x 1KB chunks via global_load_lds ----
    #pragma unroll
    for (int k = 0; k < 5; ++k) {
        int chunk = wv + k * 16;
        if (chunk < 72) {
            const unsigned char* src = (const unsigned char*)g_Ms + chunk * 1024 + lane * 16;
            __builtin_amdgcn_global_load_lds((as1_u32*)(const void*)src,
                (as3_u32*)(void*)((unsigned char*)Mlds + chunk * 1024), 16, 0, 0);
        }
    }

    int pxw = lane & 15, q = lane >> 4, rlane = lane & 15;

    // column-major tile decode: id = Lb*9 + t; bh fastest (vertical strip)
    int bb = 0, h0 = 0, w0 = 0, sbase = 0; bool edge = false, fresh = true;
    auto decode = [&](int t) {
        int id = Lb * TPB + t;
        int bh = id % 12, bw = (id / 12) % 12;
        bb = id / 144;
        h0 = bh * TH; w0 = bw * TW;
        sbase = h0 % 18;                 // window slot of pixel-row h0 (gh=h0-1 -> slot h0%18)
        edge = (bw == 0) | (bw == 11);   // col edges only; row OOB handled per-row
        fresh = (t == 0) | (bh == 0);    // strip start or column seam: full 18-row load
    };

    // ---- x stage: load (regs) + write (cvt + ds_write), circular row slots ----
    // full: items = cp(32) x rr(18 rows, gh=h0-1+rr) x f(6)  = 3456
    // slide: items = cp(32) x rr(16 rows, gh=h0+1+rr)  x f(6) = 3072
    float4 va[4], vb[4];
    auto xload = [&](int t) {
        decode(t);
        const float* xb = x + (size_t)bb * Cn * Hn * Wn;
        int nrow = fresh ? 18 : 16;
        int g0 = fresh ? (h0 - 1) : (h0 + 1);
        int items = 192 * nrow;
        #pragma unroll
        for (int k = 0; k < 4; ++k) {
            int idx = tid + (k << 10);
            if (idx >= items) break;
            int f = idx % 6;
            int rr = (idx / 6) % nrow;
            int cp = idx / (6 * nrow);
            int gh = g0 + rr;
            int gwf = w0 + f * 4 - 4;
            const float* row0 = xb + ((size_t)(cp * 2) * Hn + gh) * Wn;
            const float* row1 = row0 + (size_t)(Hn * Wn);
            bool ghok = (unsigned)gh < (unsigned)Hn;
            if (!edge && ghok) {
                va[k] = *(const float4*)(row0 + gwf);
                vb[k] = *(const float4*)(row1 + gwf);
            } else if (ghok && gwf >= 0 && gwf <= Wn - 4) {
                va[k] = *(const float4*)(row0 + gwf);
                vb[k] = *(const float4*)(row1 + gwf);
            } else {
                float t0[4], t1[4];
                #pragma unroll
                for (int j = 0; j < 4; ++j) {
                    int gw = gwf + j;
                    bool ok = ghok && (unsigned)gw < (unsigned)Wn;
                    t0[j] = ok ? row0[gw] : 0.f;
                    t1[j] = ok ? row1[gw] : 0.f;
                }
                va[k] = (float4){t0[0], t0[1], t0[2], t0[3]};
                vb[k] = (float4){t1[0], t1[1], t1[2], t1[3]};
            }
        }
    };
    auto xwrite = [&]() {
        int nrow = fresh ? 18 : 16;
        int g0 = fresh ? (h0 - 1) : (h0 + 1);
        int items = 192 * nrow;
        #pragma unroll
        for (int k = 0; k < 4; ++k) {
            int idx = tid + (k << 10);
            if (idx >= items) break;
            int f = idx % 6;
            int rr = (idx / 6) % nrow;
            int cp = idx / (6 * nrow);
            int gh = g0 + rr;
            int slot = (gh + 1) % 18;            // circular row slot
            int chunk = cp >> 2;
            int sub = (cp & 3) * 4;
            float v0[4] = {va[k].x, va[k].y, va[k].z, va[k].w};
            float v1[4] = {vb[k].x, vb[k].y, vb[k].z, vb[k].w};
            #pragma unroll
            for (int j = 0; j < 4; ++j) {
                int col = f * 4 + j - 3;
                if ((unsigned)col >= 18u) continue;
                unsigned u;
                asm("v_cvt_pk_bf16_f32 %0, %1, %2" : "=v"(u) : "v"(v0[j]), "v"(v1[j]));
                int byte = (slot * 18 + col) * 128 + ((chunk ^ ((col + 3 * slot) & 7)) * 16) + sub;
                *(unsigned*)(xsb + byte) = u;
            }
        }
    };

    xload(0);
    xwrite();
    __syncthreads();   // publishes M + x(0)

    for (int t = 0; t < TPB; ++t) {
        decode(t);
        int ch0 = h0, cw0 = w0, csb = sbase;
        if (t + 1 < TPB) xload(t + 1);   // issue next tile's loads; retire under compute

        // ---- compute tile t: R14-exact inline, barrier-free; row -> circular slot ----
        f32x4 acc[4];
        #pragma unroll
        for (int m = 0; m < 4; ++m) acc[m] = (f32x4){0.f, 0.f, 0.f, 0.f};

        #pragma unroll
        for (int sp = 0; sp < 9; ++sp) {
            const int dy = sp / 3, dx = sp % 3;
            int col = pxw + dx;
            int slot = csb + wv + dy;            // window row (h0+wv+dy-1) -> slot
            if (slot >= 18) slot -= 18;
            int bbase = (slot * 18 + col) * 128;
            int bswz = (col + 3 * slot) & 7;
            #pragma unroll
            for (int kh = 0; kh < 2; ++kh) {
                int ksl = kh * 4 + q;
                bf16x8 bfr = *(const bf16x8*)(xsb + bbase + ((ksl ^ bswz) << 4));
                const unsigned char* mrow = (const unsigned char*)Mlds + sp * 8192 +
                                            rlane * 128 + ((ksl ^ (rlane & 7)) << 4);
                __builtin_amdgcn_s_setprio(1);
                #pragma unroll
                for (int m = 0; m < 4; ++m) {
                    bf16x8 am = *(const bf16x8*)(mrow + m * 2048);
                    acc[m] = __builtin_amdgcn_mfma_f32_16x16x32_bf16(am, bfr, acc[m], 0, 0, 0);
                }
                __builtin_amdgcn_s_setprio(0);
            }
        }

        // ---- epilogue: +bias, real-only stores (wave wv owns output row ch0+wv) ----
        #pragma unroll
        for (int m = 0; m < 4; ++m) {
            int rbase = m * 16 + q * 4;
            float4 bq = *(const float4*)(g_b2 + rbase);
            float* orow = out + (((size_t)(bb * Cn + rbase)) * Hn + (ch0 + wv)) * Wn + cw0 + pxw;
            orow[0]                      = acc[m][0] + bq.x;
            orow[(size_t)Hn * Wn]        = acc[m][1] + bq.y;
            orow[(size_t)2 * Hn * Wn]    = acc[m][2] + bq.z;
            orow[(size_t)3 * Hn * Wn]    = acc[m][3] + bq.w;
        }

        __syncthreads();                 // all xsb reads for tile t done
        if (t + 1 < TPB) {
            decode(t + 1);               // restore next-tile staging params
            xwrite();                    // cvt + ds_write new rows (other slots)
        }
        __syncthreads();                 // publish x(t+1)
    }
}

extern "C" void kernel_launch(void* const* d_in, const int* in_sizes, int n_in,
                              void* d_out, int out_size, void* d_ws, size_t ws_size,
                              hipStream_t stream) {
    const float* x    = (const float*)d_in[0];
    const float* cw   = (const float*)d_in[1];
    const float* A    = (const float*)d_in[2];
    const float* D    = (const float*)d_in[3];
    const float* bias = (const float*)d_in[4];
    const int*   perm = (const int*)d_in[5];

    acdc_precompute<<<dim3(64), dim3(256), 0, stream>>>(cw, A, D, bias, perm);
    acdc_main<<<dim3(NBLKS), dim3(1024), 0, stream>>>(x, (float*)d_out);
}

// Round 19
// 92.164 us; speedup vs baseline: 2.0029x; 1.2675x over previous
//
#include <hip/hip_runtime.h>
#include <math.h>

#define Bn 16
#define Cn 64
#define Hn 192
#define Wn 192
#define NPIX (Bn * Cn * Hn * Wn)       // 37748736
#define NBLKS 256
#define ROWS 12                        // output rows per block (16 bands x 16 images)
#define SLOTB (194 * 128)              // 24832 B per window row-slot

typedef short bf16x8 __attribute__((ext_vector_type(8)));
typedef float f32x4 __attribute__((ext_vector_type(4)));
typedef __attribute__((address_space(1))) const unsigned int as1_u32;
typedef __attribute__((address_space(3))) unsigned int as3_u32;

// g_Ms[9 slices][64 rows][64 c] bf16; within a row, c-octet g stored at slot (g ^ (p&7)).
__device__ __align__(16) unsigned short g_Ms[9 * 64 * 64];
__device__ __align__(16) float g_b2[64];

static __device__ __forceinline__ unsigned short f2bf(float f) {
    union { float f; unsigned u; } x; x.f = f;
    unsigned r = x.u + 0x7fffu + ((x.u >> 16) & 1u);   // RNE
    return (unsigned short)(r >> 16);
}

__global__ void acdc_precompute(const float* __restrict__ cw, const float* __restrict__ A,
                                const float* __restrict__ D, const float* __restrict__ bias,
                                const int* __restrict__ perm) {
    __shared__ float mre[64];
    int p = blockIdx.x;
    int t = threadIdx.x;
    if (t < 64) {
        float re = 0.f;
        for (int k = 0; k < 64; ++k) {
            int a = (k * t) & 63;
            re += D[k] * cosf((float)a * 0.0981747704246810387f);  // pi/32
        }
        mre[t] = re;
    }
    __syncthreads();
    int pp = perm[p];
    for (int k0 = t; k0 < 576; k0 += 256) {
        int sp = k0 >> 6, c = k0 & 63;
        int g = c >> 3, cil = c & 7;
        float val = 0.f;
        for (int o = 0; o < 8; ++o) {
            int oc = g * 8 + o;
            float gco = mre[(pp - oc + 64) & 63] * A[oc] * (0.125f / 64.0f);
            val += gco * cw[(oc * 8 + cil) * 9 + sp];
        }
        g_Ms[((sp * 64 + p) << 6) + (((g ^ (p & 7)) << 3) | cil)] = f2bf(val);
    }
    if (p == 0 && t < 64)
        g_b2[t] = bias[perm[t]] * 0.125f;
}

// Persistent block: 1024 threads, 1 block/CU. Block = one image x 12 FULL-WIDTH rows.
// x staged one full row at a time (3-slot circular window) -> sequential 768B reads;
// out written as full channel-rows -> sequential writes. M in LDS once (72 KB).
// LDS total 148.2 KB. R14 2-barrier/row rhythm (xload early / xwrite between barriers).
__global__ __launch_bounds__(1024)
void acdc_main(const float* __restrict__ x, float* __restrict__ out) {
    __shared__ __align__(16) unsigned short Mlds[9 * 64 * 64];    // 73728 B
    __shared__ __align__(16) unsigned char xsb[3 * SLOTB];        // 74496 B

    int tid = threadIdx.x;
    int lane = tid & 63, wv = tid >> 6;
    // bijective XCD swizzle: each XCD gets 32 consecutive logical blocks = 2 whole images
    int Lb = (blockIdx.x & 7) * (NBLKS / 8) + (blockIdx.x >> 3);
    int bb = Lb >> 4;                 // image
    int h0 = (Lb & 15) * ROWS;        // row band (h0 % 3 == 0 always)

    // ---- stage M once: 72 x 1KB chunks via global_load_lds ----
    #pragma unroll
    for (int k = 0; k < 5; ++k) {
        int chunk = wv + k * 16;
        if (chunk < 72) {
            const unsigned char* src = (const unsigned char*)g_Ms + chunk * 1024 + lane * 16;
            __builtin_amdgcn_global_load_lds((as1_u32*)(const void*)src,
                (as3_u32*)(void*)((unsigned char*)Mlds + chunk * 1024), 16, 0, 0);
        }
    }

    int pxw = lane & 15, q = lane >> 4, rlane = lane & 15;
    int m = wv >> 2;                  // m-tile 0..3 (out channels m*16..m*16+15)
    int ng = wv & 3;                  // n-group: n-tiles ng, ng+4, ng+8

    const float* xb = x + (size_t)bb * Cn * Hn * Wn;

    // ---- x row stage: load one input row gh to regs / write to window slot ----
    // items = 32 ch-pairs x 50 float4-cols (floats 4f-4..4f-1); f=0/49 are pure halo zeros
    float4 va[2], vb[2];
    auto xload = [&](int gh) {
        bool ok = (unsigned)gh < (unsigned)Hn;
        int ghc = ok ? gh : 0;
        #pragma unroll
        for (int k = 0; k < 2; ++k) {
            int idx = tid + (k << 10);
            va[k] = (float4){0.f, 0.f, 0.f, 0.f};
            vb[k] = (float4){0.f, 0.f, 0.f, 0.f};
            if (idx < 1600) {
                int f = idx % 50;
                int cp = idx / 50;
                if (ok && f >= 1 && f <= 48) {
                    const float* r0 = xb + ((size_t)(2 * cp) * Hn + ghc) * Wn + (f * 4 - 4);
                    va[k] = *(const float4*)r0;
                    vb[k] = *(const float4*)(r0 + Hn * Wn);
                }
            }
        }
    };
    auto xwrite = [&](int slot) {
        #pragma unroll
        for (int k = 0; k < 2; ++k) {
            int idx = tid + (k << 10);
            if (idx >= 1600) break;
            int f = idx % 50;
            int cp = idx / 50;
            int chunk = cp >> 2, sub = (cp & 3) * 4;
            float v0[4] = {va[k].x, va[k].y, va[k].z, va[k].w};
            float v1[4] = {vb[k].x, vb[k].y, vb[k].z, vb[k].w};
            #pragma unroll
            for (int j = 0; j < 4; ++j) {
                int c2 = f * 4 - 3 + j;            // window col = global col + 1
                if ((unsigned)c2 >= 194u) continue;
                unsigned u;
                asm("v_cvt_pk_bf16_f32 %0, %1, %2" : "=v"(u) : "v"(v0[j]), "v"(v1[j]));
                int key = (c2 + (c2 >> 3) + 3 * slot) & 7;
                int byte = slot * SLOTB + c2 * 128 + ((chunk ^ key) << 4) + sub;
                *(unsigned*)(xsb + byte) = u;
            }
        }
    };

    // prologue: rows h0-1, h0, h0+1 -> slots 0,1,2  (slot(gh) = (gh+1)%3, h0%3==0)
    xload(h0 - 1); xwrite(0);
    xload(h0);     xwrite(1);
    xload(h0 + 1); xwrite(2);
    __syncthreads();   // publishes M + initial window

    int sA = 0;        // slot of gh = h-1  (== t % 3)
    for (int t = 0; t < ROWS; ++t) {
        int h = h0 + t;
        int sB = sA + 1; if (sB == 3) sB = 0;
        int sC = sB + 1; if (sC == 3) sC = 0;
        if (t < ROWS - 1) xload(h + 2);   // issue next row's loads; retire under compute

        f32x4 acc[3];
        #pragma unroll
        for (int i = 0; i < 3; ++i) acc[i] = (f32x4){0.f, 0.f, 0.f, 0.f};

        #pragma unroll
        for (int sp = 0; sp < 9; ++sp) {
            const int dy = sp / 3, dx = sp % 3;
            int slotr = (dy == 0) ? sA : (dy == 1) ? sB : sC;
            int sb = slotr * SLOTB;
            int s3 = 3 * slotr;
            int c2b = ng * 16 + pxw + dx;
            #pragma unroll
            for (int kh = 0; kh < 2; ++kh) {
                int ksl = kh * 4 + q;
                bf16x8 am = *(const bf16x8*)((const unsigned char*)Mlds + sp * 8192 +
                             rlane * 128 + ((ksl ^ (rlane & 7)) << 4) + m * 2048);
                bf16x8 bfr[3];
                #pragma unroll
                for (int i = 0; i < 3; ++i) {
                    int c2 = c2b + i * 64;
                    int key = (c2 + (c2 >> 3) + s3) & 7;
                    bfr[i] = *(const bf16x8*)(xsb + sb + c2 * 128 + ((ksl ^ key) << 4));
                }
                __builtin_amdgcn_s_setprio(1);
                #pragma unroll
                for (int i = 0; i < 3; ++i)
                    acc[i] = __builtin_amdgcn_mfma_f32_16x16x32_bf16(am, bfr[i], acc[i], 0, 0, 0);
                __builtin_amdgcn_s_setprio(0);
            }
        }

        // ---- epilogue: +bias; full-width coalesced row stores ----
        {
            int rbase = m * 16 + q * 4;
            float4 bq = *(const float4*)(g_b2 + rbase);
            float bvs[4] = {bq.x, bq.y, bq.z, bq.w};
            #pragma unroll
            for (int i = 0; i < 3; ++i) {
                int px = (ng + i * 4) * 16 + pxw;
                #pragma unroll
                for (int j = 0; j < 4; ++j)
                    out[(((size_t)(bb * Cn + rbase + j)) * Hn + h) * Wn + px] =
                        acc[i][j] + bvs[j];
            }
        }

        __syncthreads();                  // all window reads for row h done
        if (t < ROWS - 1) xwrite(sA);     // row h+2 -> slot (h+3)%3 == sA (gh=h-1's slot)
        __syncthreads();                  // publish new row
        sA = sB;
    }
}

extern "C" void kernel_launch(void* const* d_in, const int* in_sizes, int n_in,
                              void* d_out, int out_size, void* d_ws, size_t ws_size,
                              hipStream_t stream) {
    const float* x    = (const float*)d_in[0];
    const float* cw   = (const float*)d_in[1];
    const float* A    = (const float*)d_in[2];
    const float* D    = (const float*)d_in[3];
    const float* bias = (const float*)d_in[4];
    const int*   perm = (const int*)d_in[5];

    acdc_precompute<<<dim3(64), dim3(256), 0, stream>>>(cw, A, D, bias, perm);
    acdc_main<<<dim3(NBLKS), dim3(1024), 0, stream>>>(x, (float*)d_out);
}